// Round 4
// baseline (717.360 us; speedup 1.0000x reference)
//
#include <hip/hip_runtime.h>
#include <math.h>

#define Bdim 2
#define Sdim 1024
#define Hdim 64
#define DN 128
#define DRr 64
#define DV 128
#define QRk 1536
#define KRk 512
#define Tn (Bdim*Sdim)          // 2048 tokens
#define NQ (Hdim*(DN+DRr))      // 12288
#define NKV (Hdim*(DN+DV))      // 16384
#define SCALE 0.07216878364870323f

typedef __bf16 bf16_t;
typedef bf16_t bf16x8 __attribute__((ext_vector_type(8)));
typedef float f32x4 __attribute__((ext_vector_type(4)));
typedef const __attribute__((address_space(1))) unsigned int* gas_ptr;
typedef __attribute__((address_space(3))) unsigned int* las_ptr;

__device__ __forceinline__ unsigned short f2bf(float f) {
  unsigned u = __builtin_bit_cast(unsigned, f);
  u += 0x7fffu + ((u >> 16) & 1u);
  return (unsigned short)(u >> 16);
}
__device__ __forceinline__ float bf2f(unsigned short h) {
  return __builtin_bit_cast(float, (unsigned)h << 16);
}

// ---------------- fp32 -> bf16 conversion (vectorized) ----------------
__global__ void cvt_f32_bf16(const float* __restrict__ in,
                             unsigned short* __restrict__ out, int n4) {
  int i = blockIdx.x * blockDim.x + threadIdx.x;
  int stride = gridDim.x * blockDim.x;
  for (int idx = i; idx < n4; idx += stride) {
    float4 v = reinterpret_cast<const float4*>(in)[idx];
    ushort4 o;
    o.x = f2bf(v.x); o.y = f2bf(v.y); o.z = f2bf(v.z); o.w = f2bf(v.w);
    reinterpret_cast<ushort4*>(out)[idx] = o;
  }
}

// ---------------- bf16 GEMM C = A * B^T  (m97-style 128x128 tile) ----------------
// A: [M][K] bf16, B: [N][K] bf16. EPI=0: C0[row*N+col] bf16.
// EPI=1 (kv-proj): col -> h=col/256, d=col%256; d<128 -> C0 (k_nope [t][h*128+d]);
//                  d>=128 -> C1 v-transposed [b][h][d-128][t%1024].
template<int EPI>
__global__ __launch_bounds__(256) void gemm_bt(
    const unsigned short* __restrict__ A, const unsigned short* __restrict__ B,
    unsigned short* __restrict__ C0, unsigned short* __restrict__ C1,
    int M, int N, int K)
{
  __shared__ __align__(16) unsigned short lds_a[128*32];
  __shared__ __align__(16) unsigned short lds_b[128*32];
  const int t  = threadIdx.x;
  const int l  = t & 63;
  const int w  = t >> 6;
  const int wr = (w >> 1) * 64;
  const int wc = (w & 1) * 64;
  const int by = blockIdx.y * 128;
  const int bx = blockIdx.x * 128;

  f32x4 acc[4][4];
#pragma unroll
  for (int m = 0; m < 4; ++m)
#pragma unroll
    for (int n = 0; n < 4; ++n) acc[m][n] = (f32x4){0.f,0.f,0.f,0.f};

  const int lr = t >> 2;          // row within 64-row half
  const int lc = (t & 3) * 8;     // col offset (elements)
  const unsigned short* Abase = A + (size_t)by * K + lc;
  const unsigned short* Bbase = B + (size_t)bx * K + lc;
  const int rl = l & 15;
  const int kl = (l >> 4) * 8;

  for (int k0 = 0; k0 < K; k0 += 32) {
#pragma unroll
    for (int i = 0; i < 2; ++i) {
      const unsigned short* ga = Abase + (size_t)(i*64 + lr) * K + k0;
      const unsigned short* gb = Bbase + (size_t)(i*64 + lr) * K + k0;
      __builtin_amdgcn_global_load_lds((gas_ptr)ga, (las_ptr)&lds_a[i*2048 + w*512], 16, 0, 0);
      __builtin_amdgcn_global_load_lds((gas_ptr)gb, (las_ptr)&lds_b[i*2048 + w*512], 16, 0, 0);
    }
    __syncthreads();
    bf16x8 af[4], bfv[4];
#pragma unroll
    for (int m = 0; m < 4; ++m)
      af[m] = *reinterpret_cast<const bf16x8*>(&lds_a[(wr + m*16 + rl)*32 + kl]);
#pragma unroll
    for (int n = 0; n < 4; ++n)
      bfv[n] = *reinterpret_cast<const bf16x8*>(&lds_b[(wc + n*16 + rl)*32 + kl]);
#pragma unroll
    for (int m = 0; m < 4; ++m)
#pragma unroll
      for (int n = 0; n < 4; ++n)
        acc[m][n] = __builtin_amdgcn_mfma_f32_16x16x32_bf16(af[m], bfv[n], acc[m][n], 0, 0, 0);
    __syncthreads();
  }

  const int rg = (l >> 4) * 4;
#pragma unroll
  for (int m = 0; m < 4; ++m)
#pragma unroll
    for (int n = 0; n < 4; ++n)
#pragma unroll
      for (int j = 0; j < 4; ++j) {
        int row = by + wr + m*16 + rg + j;
        int col = bx + wc + n*16 + rl;
        float v = acc[m][n][j];
        if constexpr (EPI == 0) {
          C0[(size_t)row * N + col] = f2bf(v);
        } else {
          int h = col >> 8;
          int d = col & 255;
          if (d < 128) {
            C0[(size_t)row * (Hdim*DN) + h*DN + d] = f2bf(v);
          } else {
            int bb = row >> 10;
            int tt = row & 1023;
            C1[(((size_t)(bb*Hdim + h) * DV + (d - 128)) << 10) + tt] = f2bf(v);
          }
        }
      }
}

// ---------------- RoPE on q_pe slice of q buffer (in place, bf16) ----------------
__global__ void rope_q(unsigned short* __restrict__ q,
                       const float* __restrict__ cosb, const float* __restrict__ sinb) {
  int gid = blockIdx.x * blockDim.x + threadIdx.x;
  int wid = gid >> 6;
  int l = gid & 63;
  if (wid >= Tn * Hdim) return;
  int tt = wid >> 6;
  int h = wid & 63;
  unsigned short* row = q + (size_t)tt * NQ + h * (DN + DRr) + DN;
  float x = bf2f(row[l]);
  float other = __shfl_xor(x, 32, 64);
  float rot = (l < 32) ? -other : other;
  row[l] = f2bf(x * cosb[tt*64 + l] + rot * sinb[tt*64 + l]);
}

// ---------------- RoPE on PE -> k_pe (bf16) ----------------
__global__ void rope_pe(const float* __restrict__ PE,
                        const float* __restrict__ cosb, const float* __restrict__ sinb,
                        unsigned short* __restrict__ kpe) {
  int gid = blockIdx.x * blockDim.x + threadIdx.x;
  int tt = gid >> 6;
  int l = gid & 63;
  if (tt >= Tn) return;
  float x = PE[tt*64 + l];
  float other = __shfl_xor(x, 32, 64);
  float rot = (l < 32) ? -other : other;
  kpe[tt*64 + l] = f2bf(x * cosb[tt*64 + l] + rot * sinb[tt*64 + l]);
}

// ---------------- causal flash attention, 1 wave/block, QBLK=32, KBLK=32 ----------------
__global__ __launch_bounds__(64) void mla_attn(
    const unsigned short* __restrict__ qb,   // [2048][12288] (rope applied to pe slice)
    const unsigned short* __restrict__ kb,   // [2048][64*128] k_nope
    const unsigned short* __restrict__ pb,   // [2048][64]     k_pe
    const unsigned short* __restrict__ vtb,  // [2][64][128][1024] V transposed
    float* __restrict__ out)                 // [2][1024][64][128]
{
  const int bid = blockIdx.x;
  const int qt = bid & 31;
  const int h  = (bid >> 5) & 63;
  const int b  = bid >> 11;
  const int l  = threadIdx.x;
  const int rl = l & 15;
  const int kl = (l >> 4) << 3;
  const int rg = (l >> 4) << 2;
  const int q0 = qt << 5;

  __shared__ __align__(16) unsigned short lds_p[2][16*32];

  bf16x8 aq[2][6];
  const unsigned short* qp = qb + (size_t)(b*Sdim + q0) * NQ + h*(DN+DRr);
#pragma unroll
  for (int mb = 0; mb < 2; ++mb)
#pragma unroll
    for (int s = 0; s < 6; ++s)
      aq[mb][s] = *reinterpret_cast<const bf16x8*>(qp + (size_t)(mb*16 + rl)*NQ + s*32 + kl);

  f32x4 acc[2][8];
  f32x4 mrun[2], drun[2];
#pragma unroll
  for (int mb = 0; mb < 2; ++mb) {
#pragma unroll
    for (int v = 0; v < 8; ++v) acc[mb][v] = (f32x4){0.f,0.f,0.f,0.f};
#pragma unroll
    for (int j = 0; j < 4; ++j) { mrun[mb][j] = -INFINITY; drun[mb][j] = 0.f; }
  }

  const unsigned short* kp = kb + (size_t)(b*Sdim)*(Hdim*DN) + h*DN;
  const unsigned short* pp = pb + (size_t)(b*Sdim)*DRr;
  const unsigned short* vp = vtb + (size_t)(b*Hdim + h)*DV*Sdim;

  for (int kt = 0; kt <= qt; ++kt) {
    const int kbase = kt << 5;
    bf16x8 bk[2][6];
#pragma unroll
    for (int kh = 0; kh < 2; ++kh) {
      const int key = kbase + kh*16 + rl;
      const unsigned short* kr = kp + (size_t)key * (Hdim*DN);
      const unsigned short* pr = pp + (size_t)key * DRr;
#pragma unroll
      for (int s = 0; s < 4; ++s)
        bk[kh][s] = *reinterpret_cast<const bf16x8*>(kr + s*32 + kl);
#pragma unroll
      for (int s = 0; s < 2; ++s)
        bk[kh][4+s] = *reinterpret_cast<const bf16x8*>(pr + s*32 + kl);
    }
    f32x4 sc[2][2];
#pragma unroll
    for (int mb = 0; mb < 2; ++mb)
#pragma unroll
      for (int kh = 0; kh < 2; ++kh) {
        sc[mb][kh] = (f32x4){0.f,0.f,0.f,0.f};
#pragma unroll
        for (int s = 0; s < 6; ++s)
          sc[mb][kh] = __builtin_amdgcn_mfma_f32_16x16x32_bf16(aq[mb][s], bk[kh][s], sc[mb][kh], 0, 0, 0);
      }

#pragma unroll
    for (int mb = 0; mb < 2; ++mb) {
#pragma unroll
      for (int kh = 0; kh < 2; ++kh) {
        const int key = kbase + kh*16 + rl;
#pragma unroll
        for (int j = 0; j < 4; ++j) {
          const int qrow = q0 + mb*16 + rg + j;
          float sv = sc[mb][kh][j] * SCALE;
          sc[mb][kh][j] = (key <= qrow) ? sv : -INFINITY;
        }
      }
      f32x4 tm;
#pragma unroll
      for (int j = 0; j < 4; ++j) tm[j] = fmaxf(sc[mb][0][j], sc[mb][1][j]);
#pragma unroll
      for (int off = 1; off < 16; off <<= 1)
#pragma unroll
        for (int j = 0; j < 4; ++j) tm[j] = fmaxf(tm[j], __shfl_xor(tm[j], off, 64));
      f32x4 corr, ps;
#pragma unroll
      for (int j = 0; j < 4; ++j) {
        float mn = fmaxf(mrun[mb][j], tm[j]);
        corr[j] = __expf(mrun[mb][j] - mn);
        mrun[mb][j] = mn;
#pragma unroll
        for (int kh = 0; kh < 2; ++kh)
          sc[mb][kh][j] = __expf(sc[mb][kh][j] - mn);
        ps[j] = sc[mb][0][j] + sc[mb][1][j];
      }
#pragma unroll
      for (int off = 1; off < 16; off <<= 1)
#pragma unroll
        for (int j = 0; j < 4; ++j) ps[j] += __shfl_xor(ps[j], off, 64);
#pragma unroll
      for (int j = 0; j < 4; ++j) drun[mb][j] = drun[mb][j]*corr[j] + ps[j];
#pragma unroll
      for (int v = 0; v < 8; ++v)
#pragma unroll
        for (int j = 0; j < 4; ++j) acc[mb][v][j] *= corr[j];
#pragma unroll
      for (int kh = 0; kh < 2; ++kh)
#pragma unroll
        for (int j = 0; j < 4; ++j)
          lds_p[mb][(rg + j)*32 + kh*16 + rl] = f2bf(sc[mb][kh][j]);
    }
    __syncthreads();
    bf16x8 ap[2];
#pragma unroll
    for (int mb = 0; mb < 2; ++mb)
      ap[mb] = *reinterpret_cast<const bf16x8*>(&lds_p[mb][rl*32 + kl]);
#pragma unroll
    for (int v = 0; v < 8; ++v) {
      bf16x8 bv = *reinterpret_cast<const bf16x8*>(vp + (size_t)(v*16 + rl)*Sdim + kbase + kl);
#pragma unroll
      for (int mb = 0; mb < 2; ++mb)
        acc[mb][v] = __builtin_amdgcn_mfma_f32_16x16x32_bf16(ap[mb], bv, acc[mb][v], 0, 0, 0);
    }
    __syncthreads();
  }

#pragma unroll
  for (int mb = 0; mb < 2; ++mb) {
    f32x4 inv;
#pragma unroll
    for (int j = 0; j < 4; ++j) inv[j] = 1.f / drun[mb][j];
#pragma unroll
    for (int v = 0; v < 8; ++v)
#pragma unroll
      for (int j = 0; j < 4; ++j) {
        const int qrow = q0 + mb*16 + rg + j;
        out[(((size_t)(b*Sdim + qrow))*Hdim + h)*DV + v*16 + rl] = acc[mb][v][j] * inv[j];
      }
  }
}

extern "C" void kernel_launch(void* const* d_in, const int* in_sizes, int n_in,
                              void* d_out, int out_size, void* d_ws, size_t ws_size,
                              hipStream_t stream) {
  const float* Q    = (const float*)d_in[0];
  const float* KV   = (const float*)d_in[1];
  const float* PE   = (const float*)d_in[2];
  const float* WUQ  = (const float*)d_in[3];
  const float* WUKV = (const float*)d_in[4];
  const float* COS  = (const float*)d_in[5];
  const float* SIN  = (const float*)d_in[6];
  float* out = (float*)d_out;

  char* ws = (char*)d_ws;
  unsigned short* qbb   = (unsigned short*)(ws);                 //  6,291,456  Q bf16
  unsigned short* wuqb  = (unsigned short*)(ws +   6291456);     // 37,748,736  WUQ bf16
  unsigned short* kvb   = (unsigned short*)(ws +  44040192);     //  2,097,152  KV bf16
  unsigned short* wukvb = (unsigned short*)(ws +  46137344);     // 16,777,216  WUKV bf16
  unsigned short* qbuf  = (unsigned short*)(ws +  62914560);     // 50,331,648  q proj
  unsigned short* kbuf  = (unsigned short*)(ws + 113246208);     // 33,554,432  k_nope
  unsigned short* vtb   = (unsigned short*)(ws + 146800640);     // 33,554,432  V^T
  unsigned short* kpeb  = (unsigned short*)(ws + 180355072);     //    262,144  k_pe

  cvt_f32_bf16<<<1024, 256, 0, stream>>>(Q,    qbb,   (Tn*QRk)/4);
  cvt_f32_bf16<<<2048, 256, 0, stream>>>(WUQ,  wuqb,  (NQ*QRk)/4);
  cvt_f32_bf16<<<512,  256, 0, stream>>>(KV,   kvb,   (Tn*KRk)/4);
  cvt_f32_bf16<<<1024, 256, 0, stream>>>(WUKV, wukvb, (NKV*KRk)/4);

  gemm_bt<0><<<dim3(NQ/128,  Tn/128), 256, 0, stream>>>(qbb, wuqb,  qbuf, (unsigned short*)nullptr, Tn, NQ,  QRk);
  gemm_bt<1><<<dim3(NKV/128, Tn/128), 256, 0, stream>>>(kvb, wukvb, kbuf, vtb,                      Tn, NKV, KRk);

  rope_q <<<(Tn*Hdim*64)/256, 256, 0, stream>>>(qbuf, COS, SIN);
  rope_pe<<<(Tn*64)/256,      256, 0, stream>>>(PE, COS, SIN, kpeb);

  mla_attn<<<Bdim*Hdim*(Sdim/32), 64, 0, stream>>>(qbuf, kbuf, kpeb, vtb, out);
}

// Round 6
// 516.493 us; speedup vs baseline: 1.3889x; 1.3889x over previous
//
#include <hip/hip_runtime.h>
#include <math.h>

#define Bdim 2
#define Sdim 1024
#define Hdim 64
#define DN 128
#define DRr 64
#define DV 128
#define QRk 1536
#define KRk 512
#define Tn (Bdim*Sdim)          // 2048 tokens
#define NQ (Hdim*(DN+DRr))      // 12288
#define NKV (Hdim*(DN+DV))      // 16384
#define SCALE 0.07216878364870323f

// attention tiling
#define QB 128                  // q rows per block (4 waves x 32)
#define KBLK 32                 // keys per iteration
#define NTILE (Sdim/QB)         // 8
#define KSTR 200                // K LDS row stride (elements, padded from 192)
#define VSTR 40                 // V LDS row stride (padded from 32)
#define PSTR 40                 // P LDS row stride (padded from 32)

typedef __bf16 bf16_t;
typedef bf16_t bf16x8 __attribute__((ext_vector_type(8)));
typedef float f32x4 __attribute__((ext_vector_type(4)));
typedef const __attribute__((address_space(1))) unsigned int* gas_ptr;
typedef __attribute__((address_space(3))) unsigned int* las_ptr;

__device__ __forceinline__ unsigned short f2bf(float f) {
  unsigned u = __builtin_bit_cast(unsigned, f);
  u += 0x7fffu + ((u >> 16) & 1u);
  return (unsigned short)(u >> 16);
}
__device__ __forceinline__ float bf2f(unsigned short h) {
  return __builtin_bit_cast(float, (unsigned)h << 16);
}

// ---------------- fp32 -> bf16 conversion (vectorized) ----------------
__global__ void cvt_f32_bf16(const float* __restrict__ in,
                             unsigned short* __restrict__ out, int n4) {
  int i = blockIdx.x * blockDim.x + threadIdx.x;
  int stride = gridDim.x * blockDim.x;
  for (int idx = i; idx < n4; idx += stride) {
    float4 v = reinterpret_cast<const float4*>(in)[idx];
    ushort4 o;
    o.x = f2bf(v.x); o.y = f2bf(v.y); o.z = f2bf(v.z); o.w = f2bf(v.w);
    reinterpret_cast<ushort4*>(out)[idx] = o;
  }
}

// ---------------- bf16 GEMM C = A * B^T  (m97-style 128x128 tile) ----------------
template<int EPI>
__global__ __launch_bounds__(256) void gemm_bt(
    const unsigned short* __restrict__ A, const unsigned short* __restrict__ B,
    unsigned short* __restrict__ C0, unsigned short* __restrict__ C1,
    int M, int N, int K)
{
  __shared__ __align__(16) unsigned short lds_a[128*32];
  __shared__ __align__(16) unsigned short lds_b[128*32];
  const int t  = threadIdx.x;
  const int l  = t & 63;
  const int w  = t >> 6;
  const int wr = (w >> 1) * 64;
  const int wc = (w & 1) * 64;
  const int by = blockIdx.y * 128;
  const int bx = blockIdx.x * 128;

  f32x4 acc[4][4];
#pragma unroll
  for (int m = 0; m < 4; ++m)
#pragma unroll
    for (int n = 0; n < 4; ++n) acc[m][n] = (f32x4){0.f,0.f,0.f,0.f};

  const int lr = t >> 2;
  const int lc = (t & 3) * 8;
  const unsigned short* Abase = A + (size_t)by * K + lc;
  const unsigned short* Bbase = B + (size_t)bx * K + lc;
  const int rl = l & 15;
  const int kl = (l >> 4) * 8;

  for (int k0 = 0; k0 < K; k0 += 32) {
#pragma unroll
    for (int i = 0; i < 2; ++i) {
      const unsigned short* ga = Abase + (size_t)(i*64 + lr) * K + k0;
      const unsigned short* gb = Bbase + (size_t)(i*64 + lr) * K + k0;
      __builtin_amdgcn_global_load_lds((gas_ptr)ga, (las_ptr)&lds_a[i*2048 + w*512], 16, 0, 0);
      __builtin_amdgcn_global_load_lds((gas_ptr)gb, (las_ptr)&lds_b[i*2048 + w*512], 16, 0, 0);
    }
    __syncthreads();
    bf16x8 af[4], bfv[4];
#pragma unroll
    for (int m = 0; m < 4; ++m)
      af[m] = *reinterpret_cast<const bf16x8*>(&lds_a[(wr + m*16 + rl)*32 + kl]);
#pragma unroll
    for (int n = 0; n < 4; ++n)
      bfv[n] = *reinterpret_cast<const bf16x8*>(&lds_b[(wc + n*16 + rl)*32 + kl]);
#pragma unroll
    for (int m = 0; m < 4; ++m)
#pragma unroll
      for (int n = 0; n < 4; ++n)
        acc[m][n] = __builtin_amdgcn_mfma_f32_16x16x32_bf16(af[m], bfv[n], acc[m][n], 0, 0, 0);
    __syncthreads();
  }

  const int rg = (l >> 4) * 4;
#pragma unroll
  for (int m = 0; m < 4; ++m)
#pragma unroll
    for (int n = 0; n < 4; ++n)
#pragma unroll
      for (int j = 0; j < 4; ++j) {
        int row = by + wr + m*16 + rg + j;
        int col = bx + wc + n*16 + rl;
        float v = acc[m][n][j];
        if constexpr (EPI == 0) {
          C0[(size_t)row * N + col] = f2bf(v);
        } else {
          int h = col >> 8;
          int d = col & 255;
          if (d < 128) {
            C0[(size_t)row * (Hdim*DN) + h*DN + d] = f2bf(v);
          } else {
            int bb = row >> 10;
            int tt = row & 1023;
            C1[(((size_t)(bb*Hdim + h) * DV + (d - 128)) << 10) + tt] = f2bf(v);
          }
        }
      }
}

// ---------------- RoPE on q_pe slice of q buffer (in place, bf16) ----------------
__global__ void rope_q(unsigned short* __restrict__ q,
                       const float* __restrict__ cosb, const float* __restrict__ sinb) {
  int gid = blockIdx.x * blockDim.x + threadIdx.x;
  int wid = gid >> 6;
  int l = gid & 63;
  if (wid >= Tn * Hdim) return;
  int tt = wid >> 6;
  int h = wid & 63;
  unsigned short* row = q + (size_t)tt * NQ + h * (DN + DRr) + DN;
  float x = bf2f(row[l]);
  float other = __shfl_xor(x, 32, 64);
  float rot = (l < 32) ? -other : other;
  row[l] = f2bf(x * cosb[tt*64 + l] + rot * sinb[tt*64 + l]);
}

// ---------------- RoPE on PE -> k_pe (bf16) ----------------
__global__ void rope_pe(const float* __restrict__ PE,
                        const float* __restrict__ cosb, const float* __restrict__ sinb,
                        unsigned short* __restrict__ kpe) {
  int gid = blockIdx.x * blockDim.x + threadIdx.x;
  int tt = gid >> 6;
  int l = gid & 63;
  if (tt >= Tn) return;
  float x = PE[tt*64 + l];
  float other = __shfl_xor(x, 32, 64);
  float rot = (l < 32) ? -other : other;
  kpe[tt*64 + l] = f2bf(x * cosb[tt*64 + l] + rot * sinb[tt*64 + l]);
}

// ---------------- causal flash attention ----------------
// 4 waves/block, 32 q-rows/wave (QB=128/block). K/V staged in LDS shared by
// all waves. Diagonal pairing: block p does q-tiles p and 7-p => uniform 36
// K-iterations per block. 512 blocks, perfectly balanced (2/CU).
__global__ __launch_bounds__(256, 2) void mla_attn(
    const unsigned short* __restrict__ qb,   // [2048][12288] (rope applied)
    const unsigned short* __restrict__ kb,   // [2048][64*128] k_nope
    const unsigned short* __restrict__ pb,   // [2048][64]     k_pe
    const unsigned short* __restrict__ vtb,  // [2][64][128][1024] V transposed
    float* __restrict__ out)                 // [2][1024][64][128]
{
  const int bid = blockIdx.x;
  const int p  = bid & 3;          // pair index 0..3
  const int h  = (bid >> 2) & 63;
  const int b  = bid >> 8;
  const int t  = threadIdx.x;
  const int w  = t >> 6;
  const int l  = t & 63;
  const int rl = l & 15;
  const int kl = (l >> 4) << 3;
  const int rg = (l >> 4) << 2;

  __shared__ __align__(16) unsigned short lds_k[KBLK*KSTR];      // 12.8 KB
  __shared__ __align__(16) unsigned short lds_v[DV*VSTR];        // 10.2 KB
  __shared__ __align__(16) unsigned short lds_p[4][2][16*PSTR];  // 10.2 KB

  // staging maps
  const int krow = t >> 3;          // 0..31 (8 threads per K row)
  const int kc8  = (t & 7) << 3;    // element offset 0..56
  const int vrow = t >> 1;          // 0..127 (2 threads per V row)
  const int vc   = (t & 1) << 4;    // element offset 0 or 16

  const unsigned short* kp = kb + (size_t)(b*Sdim)*(Hdim*DN) + h*DN;
  const unsigned short* pp = pb + (size_t)(b*Sdim)*DRr;
  const unsigned short* vp = vtb + (size_t)(b*Hdim + h)*DV*Sdim;

  for (int half = 0; half < 2; ++half) {
    const int tt = half ? (NTILE - 1 - p) : p;   // q-tile index
    const int tb = tt * QB;                      // tile base row
    const int nkt = (tb + QB) / KBLK;            // 4*(tt+1) K-iterations
    const int qw = tb + w*32;                    // this wave's first q row

    // load Q fragments (once per tile)
    bf16x8 aq[2][6];
    const unsigned short* qp = qb + (size_t)(b*Sdim + qw) * NQ + h*(DN+DRr);
#pragma unroll
    for (int mb = 0; mb < 2; ++mb)
#pragma unroll
      for (int s = 0; s < 6; ++s)
        aq[mb][s] = *reinterpret_cast<const bf16x8*>(qp + (size_t)(mb*16 + rl)*NQ + s*32 + kl);

    f32x4 acc[2][8];
    f32x4 mrun[2], drun[2];
#pragma unroll
    for (int mb = 0; mb < 2; ++mb) {
#pragma unroll
      for (int v = 0; v < 8; ++v) acc[mb][v] = (f32x4){0.f,0.f,0.f,0.f};
#pragma unroll
      for (int j = 0; j < 4; ++j) { mrun[mb][j] = -INFINITY; drun[mb][j] = 0.f; }
    }

    for (int kt = 0; kt < nkt; ++kt) {
      const int kbase = kt * KBLK;
      // ---- stage K (dims 0..127 from k_nope, 128..191 from k_pe) + V ----
      {
        const unsigned short* krg = kp + (size_t)(kbase + krow)*(Hdim*DN);
        *reinterpret_cast<bf16x8*>(&lds_k[krow*KSTR + kc8]) =
            *reinterpret_cast<const bf16x8*>(krg + kc8);
        *reinterpret_cast<bf16x8*>(&lds_k[krow*KSTR + 64 + kc8]) =
            *reinterpret_cast<const bf16x8*>(krg + 64 + kc8);
        const unsigned short* prg = pp + (size_t)(kbase + krow)*DRr;
        *reinterpret_cast<bf16x8*>(&lds_k[krow*KSTR + 128 + kc8]) =
            *reinterpret_cast<const bf16x8*>(prg + kc8);
        const unsigned short* vrg = vp + (size_t)vrow*Sdim + kbase;
        *reinterpret_cast<bf16x8*>(&lds_v[vrow*VSTR + vc]) =
            *reinterpret_cast<const bf16x8*>(vrg + vc);
        *reinterpret_cast<bf16x8*>(&lds_v[vrow*VSTR + vc + 8]) =
            *reinterpret_cast<const bf16x8*>(vrg + vc + 8);
      }
      __syncthreads();

      // ---- QK^T ----
      f32x4 sc[2][2];
#pragma unroll
      for (int mb = 0; mb < 2; ++mb)
#pragma unroll
        for (int kh = 0; kh < 2; ++kh) sc[mb][kh] = (f32x4){0.f,0.f,0.f,0.f};
#pragma unroll
      for (int kh = 0; kh < 2; ++kh) {
        bf16x8 bk[6];
#pragma unroll
        for (int s = 0; s < 6; ++s)
          bk[s] = *reinterpret_cast<const bf16x8*>(&lds_k[(kh*16 + rl)*KSTR + s*32 + kl]);
#pragma unroll
        for (int mb = 0; mb < 2; ++mb)
#pragma unroll
          for (int s = 0; s < 6; ++s)
            sc[mb][kh] = __builtin_amdgcn_mfma_f32_16x16x32_bf16(aq[mb][s], bk[s], sc[mb][kh], 0, 0, 0);
      }

      // ---- online softmax (per-wave private) ----
#pragma unroll
      for (int mb = 0; mb < 2; ++mb) {
#pragma unroll
        for (int kh = 0; kh < 2; ++kh) {
          const int key = kbase + kh*16 + rl;
#pragma unroll
          for (int j = 0; j < 4; ++j) {
            const int qrow = qw + mb*16 + rg + j;
            float sv = sc[mb][kh][j] * SCALE;
            sc[mb][kh][j] = (key <= qrow) ? sv : -INFINITY;
          }
        }
        f32x4 tm;
#pragma unroll
        for (int j = 0; j < 4; ++j) tm[j] = fmaxf(sc[mb][0][j], sc[mb][1][j]);
#pragma unroll
        for (int off = 1; off < 16; off <<= 1)
#pragma unroll
          for (int j = 0; j < 4; ++j) tm[j] = fmaxf(tm[j], __shfl_xor(tm[j], off, 64));
        f32x4 corr, ps;
#pragma unroll
        for (int j = 0; j < 4; ++j) {
          float mn = fmaxf(mrun[mb][j], tm[j]);
          corr[j] = __expf(mrun[mb][j] - mn);
          mrun[mb][j] = mn;
#pragma unroll
          for (int kh = 0; kh < 2; ++kh)
            sc[mb][kh][j] = __expf(sc[mb][kh][j] - mn);
          ps[j] = sc[mb][0][j] + sc[mb][1][j];
        }
#pragma unroll
        for (int off = 1; off < 16; off <<= 1)
#pragma unroll
          for (int j = 0; j < 4; ++j) ps[j] += __shfl_xor(ps[j], off, 64);
#pragma unroll
        for (int j = 0; j < 4; ++j) drun[mb][j] = drun[mb][j]*corr[j] + ps[j];
#pragma unroll
        for (int v = 0; v < 8; ++v)
#pragma unroll
          for (int j = 0; j < 4; ++j) acc[mb][v][j] *= corr[j];
#pragma unroll
        for (int kh = 0; kh < 2; ++kh)
#pragma unroll
          for (int j = 0; j < 4; ++j)
            lds_p[w][mb][(rg + j)*PSTR + kh*16 + rl] = f2bf(sc[mb][kh][j]);
      }

      // ---- PV ----
      bf16x8 ap[2];
#pragma unroll
      for (int mb = 0; mb < 2; ++mb)
        ap[mb] = *reinterpret_cast<const bf16x8*>(&lds_p[w][mb][rl*PSTR + kl]);
#pragma unroll
      for (int v = 0; v < 8; ++v) {
        bf16x8 bv = *reinterpret_cast<const bf16x8*>(&lds_v[(v*16 + rl)*VSTR + kl]);
#pragma unroll
        for (int mb = 0; mb < 2; ++mb)
          acc[mb][v] = __builtin_amdgcn_mfma_f32_16x16x32_bf16(ap[mb], bv, acc[mb][v], 0, 0, 0);
      }
      __syncthreads();
    }

    // ---- epilogue ----
#pragma unroll
    for (int mb = 0; mb < 2; ++mb) {
      f32x4 inv;
#pragma unroll
      for (int j = 0; j < 4; ++j) inv[j] = 1.f / drun[mb][j];
#pragma unroll
      for (int v = 0; v < 8; ++v)
#pragma unroll
        for (int j = 0; j < 4; ++j) {
          const int qrow = qw + mb*16 + rg + j;
          out[(((size_t)(b*Sdim + qrow))*Hdim + h)*DV + v*16 + rl] = acc[mb][v][j] * inv[j];
        }
    }
  }
}

extern "C" void kernel_launch(void* const* d_in, const int* in_sizes, int n_in,
                              void* d_out, int out_size, void* d_ws, size_t ws_size,
                              hipStream_t stream) {
  const float* Q    = (const float*)d_in[0];
  const float* KV   = (const float*)d_in[1];
  const float* PE   = (const float*)d_in[2];
  const float* WUQ  = (const float*)d_in[3];
  const float* WUKV = (const float*)d_in[4];
  const float* COS  = (const float*)d_in[5];
  const float* SIN  = (const float*)d_in[6];
  float* out = (float*)d_out;

  char* ws = (char*)d_ws;
  unsigned short* qbb   = (unsigned short*)(ws);                 //  6,291,456  Q bf16
  unsigned short* wuqb  = (unsigned short*)(ws +   6291456);     // 37,748,736  WUQ bf16
  unsigned short* kvb   = (unsigned short*)(ws +  44040192);     //  2,097,152  KV bf16
  unsigned short* wukvb = (unsigned short*)(ws +  46137344);     // 16,777,216  WUKV bf16
  unsigned short* qbuf  = (unsigned short*)(ws +  62914560);     // 50,331,648  q proj
  unsigned short* kbuf  = (unsigned short*)(ws + 113246208);     // 33,554,432  k_nope
  unsigned short* vtb   = (unsigned short*)(ws + 146800640);     // 33,554,432  V^T
  unsigned short* kpeb  = (unsigned short*)(ws + 180355072);     //    262,144  k_pe

  cvt_f32_bf16<<<1024, 256, 0, stream>>>(Q,    qbb,   (Tn*QRk)/4);
  cvt_f32_bf16<<<2048, 256, 0, stream>>>(WUQ,  wuqb,  (NQ*QRk)/4);
  cvt_f32_bf16<<<512,  256, 0, stream>>>(KV,   kvb,   (Tn*KRk)/4);
  cvt_f32_bf16<<<1024, 256, 0, stream>>>(WUKV, wukvb, (NKV*KRk)/4);

  gemm_bt<0><<<dim3(NQ/128,  Tn/128), 256, 0, stream>>>(qbb, wuqb,  qbuf, (unsigned short*)nullptr, Tn, NQ,  QRk);
  gemm_bt<1><<<dim3(NKV/128, Tn/128), 256, 0, stream>>>(kvb, wukvb, kbuf, vtb,                      Tn, NKV, KRk);

  rope_q <<<(Tn*Hdim*64)/256, 256, 0, stream>>>(qbuf, COS, SIN);
  rope_pe<<<(Tn*64)/256,      256, 0, stream>>>(PE, COS, SIN, kpeb);

  mla_attn<<<Bdim*Hdim*4, 256, 0, stream>>>(qbuf, kbuf, kpeb, vtb, out);
}